// Round 1
// baseline (260.070 us; speedup 1.0000x reference)
//
#include <hip/hip_runtime.h>
#include <hip/hip_bf16.h>
#include <math.h>
#include <stdint.h>

#define BB 8
#define NC 4
#define HH 192
#define WW 192
#define HWP (HH * WW)
#define NPAIR 24            // B * (NC-1)
#define BIGI 1000000000     // matches reference BIG = 1e9 (exact in int32 and f32)

// ---------------- kernel 1: argmax over channels (softmax is monotone) -------
__global__ void k_argmax(const float* __restrict__ logits, uint8_t* __restrict__ labels) {
    int idx = blockIdx.x * blockDim.x + threadIdx.x;
    if (idx >= BB * HWP) return;
    int b = idx / HWP;
    int p = idx - b * HWP;
    const float* base = logits + (size_t)b * NC * HWP + p;
    float best = base[0];
    int bi = 0;
#pragma unroll
    for (int c = 1; c < NC; ++c) {
        float v = base[(size_t)c * HWP];
        if (v > best) { best = v; bi = c; }   // strict > keeps first max (jnp.argmax)
    }
    labels[idx] = (uint8_t)bi;
}

__device__ __forceinline__ bool fg_at(const uint8_t* labels, const int* target,
                                      int type, int b, int cls, int r, int c) {
    if ((unsigned)r >= HH || (unsigned)c >= WW) return false;  // border = background
    int off = b * HWP + r * WW + c;
    return (type == 0) ? (labels[off] == cls) : (target[off] == cls);
}

// ---- kernel 2: surface extraction + column pass of exact EDT (squared) ------
// block: 192 threads (rows), grid: (col=192, type=2, pair=24)
__global__ void k_colpass(const uint8_t* __restrict__ labels, const int* __restrict__ target,
                          uint8_t* __restrict__ surf, int* __restrict__ g2) {
    int j = blockIdx.x;
    int type = blockIdx.y;   // 0 = pred mask, 1 = gt mask
    int pair = blockIdx.z;
    int i = threadIdx.x;
    int b = pair / 3;
    int cls = pair % 3 + 1;

    bool c0 = fg_at(labels, target, type, b, cls, i, j);
    bool up = fg_at(labels, target, type, b, cls, i - 1, j);
    bool dn = fg_at(labels, target, type, b, cls, i + 1, j);
    bool lf = fg_at(labels, target, type, b, cls, i, j - 1);
    bool rt = fg_at(labels, target, type, b, cls, i, j + 1);
    bool s = c0 && !(up && dn && lf && rt);

    __shared__ uint8_t ssurf[HH];
    ssurf[i] = s ? 1 : 0;
    surf[(size_t)(pair * 2 + type) * HWP + i * WW + j] = s ? 1 : 0;
    __syncthreads();

    int best = BIGI;   // empty column -> min_i'((i-i')^2 + BIG) = BIG exactly (i'=i term)
    for (int r = 0; r < HH; ++r) {
        int d = i - r;
        int cand = ssurf[r] ? d * d : BIGI;
        best = min(best, cand);
    }
    g2[(size_t)(pair * 2 + type) * HWP + i * WW + j] = best;
}

// ---- kernel 3: row pass of exact EDT (in place) -----------------------------
// block: 192 threads (cols), grid: (row=192, type=2, pair=24)
__global__ void k_rowpass(int* __restrict__ g2) {
    int i = blockIdx.x;
    int type = blockIdx.y;
    int pair = blockIdx.z;
    int j = threadIdx.x;
    int* base = g2 + (size_t)(pair * 2 + type) * HWP + i * WW;

    __shared__ int row[WW];
    row[j] = base[j];
    __syncthreads();

    int best = 0x7FFFFFFF;
    for (int c = 0; c < WW; ++c) {
        int d = j - c;
        best = min(best, row[c] + d * d);   // <= 1e9 + 36481 < 2^31, no overflow
    }
    base[j] = best;   // safe: only LDS read after barrier, global slot is private
}

// ---- kernel 4: per-(pair,direction) percentile selection --------------------
// dir 0: field = EDT(pred surface), mask = gt surface   (gt -> pred distances)
// dir 1: field = EDT(gt surface),   mask = pred surface (pred -> gt distances)
// grid: 48 blocks of 256 threads
__global__ void k_select(const uint8_t* __restrict__ surf, const int* __restrict__ g2,
                         float* __restrict__ res) {
    int dir = blockIdx.x & 1;
    int pair = blockIdx.x >> 1;
    int fieldType = dir;
    int maskType = 1 - dir;
    const uint8_t* m = surf + (size_t)(pair * 2 + maskType) * HWP;
    const int* f = g2 + (size_t)(pair * 2 + fieldType) * HWP;

    __shared__ int hist[1024];
    __shared__ int fine[128];
    __shared__ int sn, smax, sbin, srem;
    int tid = threadIdx.x;

    for (int k = tid; k < 1024; k += blockDim.x) hist[k] = 0;
    if (tid == 0) { sn = 0; smax = -1; }
    __syncthreads();

    int cnt = 0, mx = -1;
    for (int p = tid; p < HWP; p += blockDim.x) {
        if (m[p]) {
            int v = f[p];
            cnt++;
            mx = max(mx, v);
            atomicAdd(&hist[min(v >> 7, 1023)], 1);
        }
    }
    if (cnt) { atomicAdd(&sn, cnt); atomicMax(&smax, mx); }
    __syncthreads();

    if (tid == 0) {
        int n = sn;
        if (n == 0) {
            sbin = -1;
        } else {
            // replicate jnp: idx = clip(ceil(f32(0.95)*f32(n)) - 1, 0, ...); k = idx+1
            float kf = ceilf(0.95f * (float)n);
            int k = (int)kf;
            if (k < 1) k = 1;
            if (k > n) k = n;
            int cum = 0, bsel = 0, rem = k;
            for (int b2 = 0; b2 < 1024; ++b2) {
                if (cum + hist[b2] >= k) { bsel = b2; rem = k - cum; break; }
                cum += hist[b2];
            }
            sbin = bsel; srem = rem;
        }
    }
    __syncthreads();
    for (int k = tid; k < 128; k += blockDim.x) fine[k] = 0;
    __syncthreads();

    int bsel = sbin;
    if (bsel >= 0) {
        for (int p = tid; p < HWP; p += blockDim.x) {
            if (m[p]) {
                int v = f[p];
                if (min(v >> 7, 1023) == bsel) atomicAdd(&fine[v & 127], 1);
            }
        }
    }
    __syncthreads();

    if (tid == 0) {
        float r100, r95;
        if (sn == 0) {
            r100 = INFINITY; r95 = INFINITY;   // percentile over empty mask -> inf
        } else {
            r100 = sqrtf((float)smax);
            int cum = 0, lo = 0, rem = srem;
            for (int t = 0; t < 128; ++t) {
                cum += fine[t];
                if (cum >= rem) { lo = t; break; }
            }
            int v95 = (bsel << 7) | lo;
            r95 = sqrtf((float)v95);
        }
        res[(pair * 2 + dir) * 2 + 0] = r100;
        res[(pair * 2 + dir) * 2 + 1] = r95;
    }
}

// ---- kernel 5: robust max across directions, mean over pairs ----------------
__global__ void k_final(const float* __restrict__ res, float* __restrict__ out) {
    if (threadIdx.x == 0 && blockIdx.x == 0) {
        float s100 = 0.0f, s95 = 0.0f;
        for (int p = 0; p < NPAIR; ++p) {
            float a100 = fmaxf(res[(p * 2 + 0) * 2 + 0], res[(p * 2 + 1) * 2 + 0]);
            float a95  = fmaxf(res[(p * 2 + 0) * 2 + 1], res[(p * 2 + 1) * 2 + 1]);
            s100 += a100;
            s95  += a95;
        }
        out[0] = s100 / (float)NPAIR;
        out[1] = s95  / (float)NPAIR;
    }
}

extern "C" void kernel_launch(void* const* d_in, const int* in_sizes, int n_in,
                              void* d_out, int out_size, void* d_ws, size_t ws_size,
                              hipStream_t stream) {
    const float* logits = (const float*)d_in[0];
    const int* target = (const int*)d_in[1];
    float* out = (float*)d_out;

    uint8_t* ws = (uint8_t*)d_ws;
    uint8_t* labels = ws;                                   // 294912 B
    uint8_t* surf   = ws + 294912;                          // 24*2*HWP = 1769472 B
    int*     g2     = (int*)(ws + 2064384);                 // 24*2*HWP*4 = 7077888 B
    float*   res    = (float*)(ws + 2064384 + 7077888);     // 24*2*2 floats

    k_argmax<<<(BB * HWP + 255) / 256, 256, 0, stream>>>(logits, labels);
    k_colpass<<<dim3(WW, 2, NPAIR), HH, 0, stream>>>(labels, target, surf, g2);
    k_rowpass<<<dim3(HH, 2, NPAIR), WW, 0, stream>>>(g2);
    k_select<<<NPAIR * 2, 256, 0, stream>>>(surf, g2, res);
    k_final<<<1, 64, 0, stream>>>(res, out);
}

// Round 2
// 232.070 us; speedup vs baseline: 1.1207x; 1.1207x over previous
//
#include <hip/hip_runtime.h>
#include <hip/hip_bf16.h>
#include <math.h>
#include <stdint.h>
#include <limits.h>

#define BB 8
#define NC 4
#define HH 192
#define WW 192
#define HWP (HH * WW)
#define NPAIR 24            // B * (NC-1)
#define BIGI 1000000000     // matches reference BIG = 1e9 (exact in int32 and f32)

// ---------------- kernel 1: argmax over channels (softmax is monotone) -------
__global__ void k_argmax(const float* __restrict__ logits, uint8_t* __restrict__ labels) {
    int idx = blockIdx.x * blockDim.x + threadIdx.x;
    if (idx >= BB * HWP) return;
    int b = idx / HWP;
    int p = idx - b * HWP;
    const float* base = logits + (size_t)b * NC * HWP + p;
    float best = base[0];
    int bi = 0;
#pragma unroll
    for (int c = 1; c < NC; ++c) {
        float v = base[(size_t)c * HWP];
        if (v > best) { best = v; bi = c; }   // strict > keeps first max (jnp.argmax)
    }
    labels[idx] = (uint8_t)bi;
}

__device__ __forceinline__ bool fg_at(const uint8_t* labels, const int* target,
                                      int type, int b, int cls, int r, int c) {
    if ((unsigned)r >= HH || (unsigned)c >= WW) return false;  // border = background
    int off = b * HWP + r * WW + c;
    return (type == 0) ? (labels[off] == cls) : (target[off] == cls);
}

// ---- kernel 2: surface extraction + column pass of exact EDT (squared) ------
// block: 192 threads (rows), grid: (col=192, type=2, pair=24)
__global__ void k_colpass(const uint8_t* __restrict__ labels, const int* __restrict__ target,
                          uint8_t* __restrict__ surf, int* __restrict__ g2) {
    int j = blockIdx.x;
    int type = blockIdx.y;   // 0 = pred mask, 1 = gt mask
    int pair = blockIdx.z;
    int i = threadIdx.x;
    int b = pair / 3;
    int cls = pair % 3 + 1;

    bool c0 = fg_at(labels, target, type, b, cls, i, j);
    bool up = fg_at(labels, target, type, b, cls, i - 1, j);
    bool dn = fg_at(labels, target, type, b, cls, i + 1, j);
    bool lf = fg_at(labels, target, type, b, cls, i, j - 1);
    bool rt = fg_at(labels, target, type, b, cls, i, j + 1);
    bool s = c0 && !(up && dn && lf && rt);

    __shared__ uint8_t ssurf[HH];
    ssurf[i] = s ? 1 : 0;
    surf[(size_t)(pair * 2 + type) * HWP + i * WW + j] = s ? 1 : 0;
    __syncthreads();

    int best = BIGI;   // empty column -> min_i'((i-i')^2 + BIG) = BIG exactly (i'=i term)
    for (int r = 0; r < HH; ++r) {
        int d = i - r;
        int cand = ssurf[r] ? d * d : BIGI;
        best = min(best, cand);
    }
    g2[(size_t)(pair * 2 + type) * HWP + i * WW + j] = best;
}

// ---- kernel 3: row pass of exact EDT + fused masked compaction --------------
// For field type t (EDT of surface t), the consumer mask is surface t^1:
//   dir 0: field = EDT(pred surf, t=0), mask = gt surf   (gt -> pred)
//   dir 1: field = EDT(gt surf,  t=1), mask = pred surf  (pred -> gt)
// So list index pd = pair*2 + type directly matches dir.
// block: 192 threads (cols), grid: (row=192, type=2, pair=24)
__global__ void k_rowpass(const int* __restrict__ g2, const uint8_t* __restrict__ surf,
                          int* __restrict__ list, int* __restrict__ cnt) {
    int i = blockIdx.x;
    int type = blockIdx.y;
    int pair = blockIdx.z;
    int j = threadIdx.x;
    int pd = pair * 2 + type;
    const int* base = g2 + (size_t)pd * HWP + i * WW;

    __shared__ int row[WW];
    row[j] = base[j];
    __syncthreads();

    int best = INT_MAX;
    for (int c = 0; c < WW; ++c) {
        int d = j - c;
        best = min(best, row[c] + d * d);   // <= 1e9 + 36481 < 2^31, no overflow
    }

    // compact: append best to list[pd] where the OTHER surface is set
    uint8_t msk = surf[(size_t)(pair * 2 + (type ^ 1)) * HWP + i * WW + j];
    __shared__ int lbase, lcount;
    if (j == 0) lcount = 0;
    __syncthreads();
    int my = -1;
    if (msk) my = atomicAdd(&lcount, 1);
    __syncthreads();
    if (j == 0 && lcount > 0) lbase = atomicAdd(&cnt[pd], lcount);
    __syncthreads();
    if (my >= 0) list[(size_t)pd * HWP + lbase + my] = best;
}

// ---- kernel 4: per-(pair,dir) percentile selection over compact list --------
// 48 blocks of 256 threads; n is ~1-4k (surface voxel count), list order irrelevant.
__global__ void k_pick(const int* __restrict__ list, const int* __restrict__ cnt,
                       float* __restrict__ res) {
    int pd = blockIdx.x;
    const int* L = list + (size_t)pd * HWP;
    int n = cnt[pd];

    __shared__ int hist[1024];
    __shared__ int fine[128];
    __shared__ int smax, sbin, srem;
    int tid = threadIdx.x;

    for (int k = tid; k < 1024; k += 256) hist[k] = 0;
    if (tid == 0) smax = -1;
    __syncthreads();

    int mx = -1;
    for (int p = tid; p < n; p += 256) {
        int v = L[p];
        mx = max(mx, v);
        atomicAdd(&hist[min(v >> 7, 1023)], 1);
    }
    if (mx >= 0) atomicMax(&smax, mx);
    __syncthreads();

    if (tid == 0) {
        if (n == 0) {
            sbin = -1;
        } else {
            // replicate jnp: idx = clip(ceil(f32(0.95)*f32(n)) - 1, 0, ...); k = idx+1
            float kf = ceilf(0.95f * (float)n);
            int k = (int)kf;
            if (k < 1) k = 1;
            if (k > n) k = n;
            int cum = 0;
            for (int b2 = 0; b2 < 1024; ++b2) {
                if (cum + hist[b2] >= k) { sbin = b2; srem = k - cum; break; }
                cum += hist[b2];
            }
        }
    }
    __syncthreads();
    for (int k = tid; k < 128; k += 256) fine[k] = 0;
    __syncthreads();

    int bsel = sbin;
    if (n > 0) {
        for (int p = tid; p < n; p += 256) {
            int v = L[p];
            if (min(v >> 7, 1023) == bsel) atomicAdd(&fine[v & 127], 1);
        }
    }
    __syncthreads();

    if (tid == 0) {
        float r100, r95;
        if (n == 0) {
            r100 = INFINITY; r95 = INFINITY;   // percentile over empty mask -> inf
        } else {
            r100 = sqrtf((float)smax);
            int cum = 0, lo = 0, rem = srem;
            for (int t = 0; t < 128; ++t) {
                cum += fine[t];
                if (cum >= rem) { lo = t; break; }
            }
            // real d^2 <= 72962 -> coarse bin <= 570; bin 1023 can only hold BIGI
            int v95 = (bsel == 1023) ? BIGI : ((bsel << 7) | lo);
            r95 = sqrtf((float)v95);
        }
        res[pd * 2 + 0] = r100;
        res[pd * 2 + 1] = r95;
    }
}

// ---- kernel 5: robust max across directions, mean over pairs ----------------
__global__ void k_final(const float* __restrict__ res, float* __restrict__ out) {
    if (threadIdx.x == 0 && blockIdx.x == 0) {
        float s100 = 0.0f, s95 = 0.0f;
        for (int p = 0; p < NPAIR; ++p) {
            float a100 = fmaxf(res[(p * 2 + 0) * 2 + 0], res[(p * 2 + 1) * 2 + 0]);
            float a95  = fmaxf(res[(p * 2 + 0) * 2 + 1], res[(p * 2 + 1) * 2 + 1]);
            s100 += a100;
            s95  += a95;
        }
        out[0] = s100 / (float)NPAIR;
        out[1] = s95  / (float)NPAIR;
    }
}

extern "C" void kernel_launch(void* const* d_in, const int* in_sizes, int n_in,
                              void* d_out, int out_size, void* d_ws, size_t ws_size,
                              hipStream_t stream) {
    const float* logits = (const float*)d_in[0];
    const int* target = (const int*)d_in[1];
    float* out = (float*)d_out;

    uint8_t* ws = (uint8_t*)d_ws;
    uint8_t* labels = ws;                                   // 294912 B
    uint8_t* surf   = ws + 294912;                          // 48*HWP      = 1769472 B
    int*     g2     = (int*)(ws + 2064384);                 // 48*HWP*4    = 7077888 B
    int*     list   = (int*)(ws + 9142272);                 // 48*HWP*4    = 7077888 B
    int*     cnt    = (int*)(ws + 16220160);                // 48 ints     = 192 B
    float*   res    = (float*)(ws + 16220352);              // 96 floats   = 384 B

    hipMemsetAsync(cnt, 0, 192, stream);   // ws is re-poisoned 0xAA before every call

    k_argmax<<<(BB * HWP + 255) / 256, 256, 0, stream>>>(logits, labels);
    k_colpass<<<dim3(WW, 2, NPAIR), HH, 0, stream>>>(labels, target, surf, g2);
    k_rowpass<<<dim3(HH, 2, NPAIR), WW, 0, stream>>>(g2, surf, list, cnt);
    k_pick<<<NPAIR * 2, 256, 0, stream>>>(list, cnt, res);
    k_final<<<1, 64, 0, stream>>>(res, out);
}